// Round 18
// baseline (1381.071 us; speedup 1.0000x reference)
//
#include <hip/hip_runtime.h>
#include <hip/hip_bf16.h>
#include <cstdint>

typedef __bf16 bf16;
typedef __bf16 bf16x8 __attribute__((ext_vector_type(8)));
typedef float f32x4 __attribute__((ext_vector_type(4)));
typedef unsigned int u32;
typedef unsigned short u16;

#define DEV static __device__ __forceinline__

DEV float bfbits2f(u32 bits) { return __builtin_bit_cast(float, bits << 16); }
DEV u16 f2bfbits(float f) {
  u32 u = __builtin_bit_cast(u32, f);
  u32 r = (u + 0x7fffu + ((u >> 16) & 1u)) >> 16;
  return (u16)r;
}

// ---------------- dtype probe: bf16 data has bf16-exponent-shaped low u16 ----------------
__global__ __launch_bounds__(256) void probe_k(const u32* __restrict__ x, u32* __restrict__ flag) {
  __shared__ int cnt[256];
  int t = threadIdx.x;
  int c = 0;
#pragma unroll
  for (int i = 0; i < 4; ++i) {
    u32 u = x[t * 4 + i];
    u32 e = (u >> 7) & 0xFF;  // exponent field if low u16 were a bf16
    c += (e >= 110 && e <= 140) ? 1 : 0;
  }
  cnt[t] = c;
  __syncthreads();
  for (int s = 128; s > 0; s >>= 1) {
    if (t < s) cnt[t] += cnt[t + s];
    __syncthreads();
  }
  if (t == 0) flag[0] = (cnt[0] > 512) ? 1u : 0u;  // 1 = bf16 inputs, 0 = fp32 inputs
}

// ---------------- small param convert -> canonical f32 (8 vectors, 4992 floats) ----------
__global__ __launch_bounds__(256) void cvt_params_k(const void* p0, const void* p1,
                                                    const void* p2, const void* p3,
                                                    const void* p4, const void* p5,
                                                    const void* p6, const void* p7,
                                                    float* __restrict__ out,
                                                    const u32* __restrict__ flag) {
  int i = blockIdx.x * 256 + threadIdx.x;
  if (i >= 4992) return;
  const int bounds[9] = {0, 1152, 1536, 3072, 3456, 3840, 4224, 4608, 4992};
  const void* ps[8] = {p0, p1, p2, p3, p4, p5, p6, p7};
  int seg = 0;
  while (i >= bounds[seg + 1]) ++seg;
  int off = i - bounds[seg];
  bool isbf = flag[0] != 0;
  out[i] = isbf ? bfbits2f(((const u16*)ps[seg])[off]) : ((const float*)ps[seg])[off];
}

// ---------------- weight transpose+convert ([R][C] f32|bf16 -> [C][R] bf16) --------------
__global__ __launch_bounds__(256) void transpose_k(const void* __restrict__ in,
                                                   u16* __restrict__ out, int R, int Cc,
                                                   const u32* __restrict__ flag) {
  bool isbf = flag[0] != 0;
  __shared__ u16 tile[32][33];
  int bx = blockIdx.x * 32, by = blockIdx.y * 32;
  int tx = threadIdx.x & 31, ty = threadIdx.x >> 5;
#pragma unroll
  for (int i = 0; i < 32; i += 8) {
    size_t idx = (size_t)(by + ty + i) * Cc + bx + tx;
    u16 v = isbf ? ((const u16*)in)[idx] : f2bfbits(((const float*)in)[idx]);
    tile[ty + i][tx] = v;
  }
  __syncthreads();
#pragma unroll
  for (int i = 0; i < 32; i += 8)
    out[(size_t)(bx + ty + i) * R + by + tx] = tile[tx][ty + i];
}

// ---------------- LayerNorm over C=384, chunk-local bf16 output ----------------
// RAWSRC=1: input is raw d_in x (flag-aware f32|bf16); RAWSRC=0: internal bf16.
// windowed=1: out row = windowpartition(t) - t0 ; windowed=0: out row = t - t0
template <int RAWSRC>
__global__ __launch_bounds__(256) void ln_kernel(const void* __restrict__ xv,
                                                 const float* __restrict__ g,
                                                 const float* __restrict__ b,
                                                 u32* __restrict__ out,
                                                 const u32* __restrict__ flag,
                                                 int windowed, int t0) {
  const int t = t0 + blockIdx.x * 4 + (threadIdx.x >> 6);
  const int lane = threadIdx.x & 63;
  const int e0 = lane * 6;
  float f[6];
  if (RAWSRC) {
    if (flag[0] != 0) {
      const u16* xb = (const u16*)xv + (size_t)t * 384 + e0;
#pragma unroll
      for (int j = 0; j < 6; ++j) f[j] = bfbits2f(xb[j]);
    } else {
      const float* xf = (const float*)xv + (size_t)t * 384 + e0;
#pragma unroll
      for (int j = 0; j < 6; ++j) f[j] = xf[j];
    }
  } else {
    const u32* xr = (const u32*)xv + (size_t)t * 192 + lane * 3;
#pragma unroll
    for (int j = 0; j < 3; ++j) {
      u32 u = xr[j];
      f[2 * j] = bfbits2f(u & 0xffff);
      f[2 * j + 1] = bfbits2f(u >> 16);
    }
  }
  float s = 0.f, q = 0.f;
#pragma unroll
  for (int j = 0; j < 6; ++j) { s += f[j]; q += f[j] * f[j]; }
#pragma unroll
  for (int o = 1; o < 64; o <<= 1) { s += __shfl_xor(s, o); q += __shfl_xor(q, o); }
  float mean = s * (1.0f / 384.0f);
  float var = q * (1.0f / 384.0f) - mean * mean;
  float rstd = rsqrtf(var + 1e-5f);
  int orow;
  if (windowed) {
    int bb = t / 3136, rem = t % 3136;
    int hh = rem / 56, ww = rem % 56;
    orow = (bb * 64 + (hh / 7) * 8 + (ww / 7)) * 49 + (hh % 7) * 7 + (ww % 7) - t0;
  } else {
    orow = t - t0;
  }
  u32* orp = out + (size_t)orow * 192 + lane * 3;
#pragma unroll
  for (int j = 0; j < 3; ++j) {
    float ye = (f[2 * j] - mean) * rstd * g[e0 + 2 * j] + b[e0 + 2 * j];
    float yo = (f[2 * j + 1] - mean) * rstd * g[e0 + 2 * j + 1] + b[e0 + 2 * j + 1];
    orp[j] = (u32)f2bfbits(ye) | ((u32)f2bfbits(yo) << 16);
  }
}

// ---------------- 64x128 GEMM, one LDS drain per K=384 chunk ------------------------------
// A (big stream) staged once per 384-K-chunk into 48KB LDS (T2-swizzled via pre-permuted
// global source). B (small L2-hot weight panel) preloaded into REGISTERS (24 x bf16x8)
// before the drain — its L2 latency hides under the A drain. K-loop is then pure
// ds_read+MFMA with no memory waits. Drains per block: K/384 (1 for K=384, 4 for 1536)
// vs K/64 before. 1-D grid + bijective XCD swizzle, tN fastest (A-tile sharers adjacent).
// MODE 0: C(bf16) = A*B + bias                          (qkv)
// MODE 1: C(bf16)[raw(rowOff+row)] = A*B + bias + res   (proj; res = raw x, flag-aware)
// MODE 2: C(bf16) = gelu(A*B + bias)                    (mlp1)
// MODE 3: C(d_out + rowOff, flag-aware) = A*B + bias + res(bf16 chunk-local)  (mlp2)
template <int MODE>
__global__ __launch_bounds__(256, 3) void gemm64(const bf16* __restrict__ A,
                                                 const bf16* __restrict__ BT,
                                                 void* __restrict__ Cv,
                                                 const float* __restrict__ bias,
                                                 const void* __restrict__ resv,
                                                 const u32* __restrict__ flag,
                                                 int ldA, int ldC, int K, int rowOff,
                                                 int nN) {
  // XCD-chunk swizzle (bijective for any nwg; m204)
  const int nwg = (int)gridDim.x;
  const int bid = (int)blockIdx.x;
  const int q = nwg >> 3, r = nwg & 7;
  const int xcd = bid & 7, lid = bid >> 3;
  const int wg = (xcd < r ? xcd * (q + 1) : r * (q + 1) + (xcd - r) * q) + lid;
  const int tN = wg % nN, tM = wg / nN;

  const int tid = threadIdx.x;
  const int lane = tid & 63, wave = tid >> 6;   // 4 waves; each owns 32 cols
  const int li = lane & 15, gq = lane >> 4;
  const bool isbf = flag[0] != 0;

  __shared__ bf16 As[64 * 384];   // 48KB

  f32x4 acc[4][2] = {};

  const bf16* aTile = A + (size_t)tM * 64 * ldA;
  const int colbase = tN * 128 + wave * 32;

  for (int kc = 0; kc < K; kc += 384) {
    if (kc) __syncthreads();  // prior chunk's compute done before overwriting As

    // B fragments -> registers (weights, L2-hot); issued BEFORE the A drain
    bf16x8 breg[12][2];
#pragma unroll
    for (int ks = 0; ks < 12; ++ks)
#pragma unroll
      for (int n = 0; n < 2; ++n)
        breg[ks][n] = *(const bf16x8*)(BT + (size_t)(colbase + n * 16 + li) * K + kc + ks * 32 + gq * 8);

    // A stage: 3072 granules / 256 threads = 12 each; T2 swizzle on the global source
#pragma unroll
    for (int it = 0; it < 12; ++it) {
      int c = it * 256 + tid;
      int row = c / 48, g = c % 48;
      int gs = (g & ~7) | ((g & 7) ^ (row & 7));
      __builtin_amdgcn_global_load_lds(
          (const __attribute__((address_space(1))) void*)(aTile + (size_t)row * ldA + kc + gs * 8),
          (__attribute__((address_space(3))) void*)(As + (size_t)c * 8), 16, 0, 0);
    }
    __syncthreads();  // the ONE drain per chunk (B regs land under it too)

#pragma unroll
    for (int ks = 0; ks < 12; ++ks) {
      bf16x8 af[4];
#pragma unroll
      for (int m = 0; m < 4; ++m) {
        int arow = m * 16 + li;
        int g0 = ks * 4 + gq;
        int gs = (g0 & ~7) | ((g0 & 7) ^ (arow & 7));
        af[m] = *(const bf16x8*)(As + (size_t)arow * 384 + gs * 8);
      }
#pragma unroll
      for (int m = 0; m < 4; ++m)
#pragma unroll
        for (int n = 0; n < 2; ++n)
          acc[m][n] = __builtin_amdgcn_mfma_f32_16x16x32_bf16(af[m], breg[ks][n], acc[m][n], 0, 0, 0);
    }
  }

#pragma unroll
  for (int m = 0; m < 4; ++m) {
#pragma unroll
    for (int r2 = 0; r2 < 4; ++r2) {
      int row = tM * 64 + m * 16 + gq * 4 + r2;
      size_t crow;
      if (MODE == 1) {
        int gg = rowOff + row;
        int win = gg / 49, n = gg % 49;
        int bb = win >> 6, wi = win & 63;
        int hh = (wi >> 3) * 7 + n / 7;
        int ww = (wi & 7) * 7 + n % 7;
        crow = (size_t)(bb * 3136 + hh * 56 + ww);
      } else {
        crow = (size_t)row;
      }
#pragma unroll
      for (int n = 0; n < 2; ++n) {
        int col = colbase + n * 16 + li;
        size_t idx = crow * (size_t)ldC + col;
        float v = acc[m][n][r2] + bias[col];
        if (MODE == 2) v = 0.5f * v * (1.0f + erff(v * 0.70710678118654752f));
        if (MODE == 1)
          v += isbf ? bfbits2f(((const u16*)resv)[idx]) : ((const float*)resv)[idx];
        if (MODE == 3) v += bfbits2f(((const u16*)resv)[idx]);
        if (MODE == 3) {
          size_t oidx = idx + (size_t)rowOff * 384;
          if (isbf) ((u16*)Cv)[oidx] = f2bfbits(v);
          else ((float*)Cv)[oidx] = v;
        } else {
          ((u16*)Cv)[idx] = f2bfbits(v);
        }
      }
    }
  }
}

// ---------------- window attention: one wave per (window, head) ----------------
// qkv rows are window-ordered [nWin*49][1152] bf16; cols = which*384 + head*32 + d
__global__ __launch_bounds__(256, 2) void attn_kernel(const bf16* __restrict__ qkv,
                                                      bf16* __restrict__ out) {
  __shared__ bf16 smem[4 * 6912];  // per wave: P[64][72] + VT[32][72]
  const int wave = threadIdx.x >> 6;
  const int lane = threadIdx.x & 63;
  const int unit = blockIdx.x * 4 + wave;
  const int win = unit / 12, head = unit % 12;
  bf16* P = smem + wave * 6912;
  bf16* VT = P + 64 * 72;

  const size_t base = (size_t)win * 49 * 1152 + head * 32;
  const bf16* Qp = qkv + base;
  const bf16* Kp = qkv + base + 384;
  const bf16* Vp = qkv + base + 768;

  const int gq = lane >> 4, li = lane & 15;

  // stage V^T into LDS (zero-pad m in [49,64))
  {
    int d = lane & 31, half = lane >> 5;
#pragma unroll
    for (int i = 0; i < 32; ++i) {
      int m = i * 2 + half;
      bf16 v = (m < 49) ? Vp[(size_t)m * 1152 + d] : (bf16)0.0f;
      VT[d * 72 + m] = v;
    }
  }

  // S = Q K^T (49 padded to 64; rows clamped)
  f32x4 s[4][4] = {};
  bf16x8 qf[4], kf[4];
#pragma unroll
  for (int i = 0; i < 4; ++i) {
    int qr = i * 16 + li; if (qr > 48) qr = 48;
    qf[i] = *(const bf16x8*)(Qp + (size_t)qr * 1152 + gq * 8);
    kf[i] = *(const bf16x8*)(Kp + (size_t)qr * 1152 + gq * 8);
  }
#pragma unroll
  for (int i = 0; i < 4; ++i)
#pragma unroll
    for (int j = 0; j < 4; ++j)
      s[i][j] = __builtin_amdgcn_mfma_f32_16x16x32_bf16(qf[i], kf[j], s[i][j], 0, 0, 0);

  __syncthreads();  // V^T staging visible before PV reads

  // softmax per row n = i*16 + gq*4 + r; cols m = tj*16 + li (mask m>=49: tj==3, li>=1)
  const float scale = 0.17677669529663687f;  // 1/sqrt(32)
#pragma unroll
  for (int i = 0; i < 4; ++i) {
#pragma unroll
    for (int r = 0; r < 4; ++r) {
      float v0 = s[i][0][r] * scale, v1 = s[i][1][r] * scale;
      float v2 = s[i][2][r] * scale, v3 = s[i][3][r] * scale;
      if (li >= 1) v3 = -1e30f;
      float mx = fmaxf(fmaxf(v0, v1), fmaxf(v2, v3));
#pragma unroll
      for (int o = 1; o < 16; o <<= 1) mx = fmaxf(mx, __shfl_xor(mx, o));
      v0 = __expf(v0 - mx); v1 = __expf(v1 - mx);
      v2 = __expf(v2 - mx); v3 = __expf(v3 - mx);
      float sum = v0 + v1 + v2 + v3;
#pragma unroll
      for (int o = 1; o < 16; o <<= 1) sum += __shfl_xor(sum, o);
      float inv = 1.0f / sum;
      int n = i * 16 + gq * 4 + r;
      P[n * 72 + li]      = (bf16)(v0 * inv);
      P[n * 72 + 16 + li] = (bf16)(v1 * inv);
      P[n * 72 + 32 + li] = (bf16)(v2 * inv);
      P[n * 72 + 48 + li] = (bf16)(v3 * inv);
    }
  }

  __syncthreads();  // P writes visible before PV reads

  // O = P * V
  f32x4 o[4][2] = {};
#pragma unroll
  for (int ms = 0; ms < 2; ++ms) {
    bf16x8 pf[4], vf[2];
#pragma unroll
    for (int i = 0; i < 4; ++i)
      pf[i] = *(const bf16x8*)(P + (i * 16 + li) * 72 + ms * 32 + gq * 8);
#pragma unroll
    for (int dt = 0; dt < 2; ++dt)
      vf[dt] = *(const bf16x8*)(VT + (dt * 16 + li) * 72 + ms * 32 + gq * 8);
#pragma unroll
    for (int i = 0; i < 4; ++i)
#pragma unroll
      for (int dt = 0; dt < 2; ++dt)
        o[i][dt] = __builtin_amdgcn_mfma_f32_16x16x32_bf16(pf[i], vf[dt], o[i][dt], 0, 0, 0);
  }

#pragma unroll
  for (int i = 0; i < 4; ++i) {
#pragma unroll
    for (int r = 0; r < 4; ++r) {
      int n = i * 16 + gq * 4 + r;
      if (n < 49) {
#pragma unroll
        for (int dt = 0; dt < 2; ++dt) {
          int d = dt * 16 + li;
          out[((size_t)win * 49 + n) * 384 + head * 32 + d] = (bf16)o[i][dt][r];
        }
      }
    }
  }
}

// ---------------- host ----------------
extern "C" void kernel_launch(void* const* d_in, const int* in_sizes, int n_in,
                              void* d_out, int out_size, void* d_ws, size_t ws_size,
                              hipStream_t stream) {
  const void* x      = d_in[0];
  const void* ln1_g  = d_in[1];
  const void* ln1_b  = d_in[2];
  const void* qkv_w  = d_in[3];
  const void* qkv_b  = d_in[4];
  const void* proj_w = d_in[5];
  const void* proj_b = d_in[6];
  const void* ln2_g  = d_in[7];
  const void* ln2_b  = d_in[8];
  const void* mlp_w1 = d_in[9];
  const void* mlp_b1 = d_in[10];
  const void* mlp_w2 = d_in[11];
  const void* mlp_b2 = d_in[12];

  // ws layout (bytes):
  //   0        flag (u32, padded to 256)
  //   256      transposed bf16 weights (3,538,944)
  //   3539200  canonical f32 params (4992 floats)
  //   3559168  x2 internal bf16 (77,070,336)
  //   80629504 phase region (adaptive chunks)
  char* ws = (char*)d_ws;
  u32* flag = (u32*)ws;
  bf16* qkvwT  = (bf16*)(ws + 256);
  bf16* projwT = qkvwT + 1152 * 384;
  bf16* w1T    = projwT + 384 * 384;
  bf16* w2T    = w1T + 1536 * 384;
  float* pF    = (float*)(ws + 3539200);
  float* qkv_bF  = pF;
  float* proj_bF = pF + 1152;
  float* mlp_b1F = pF + 1536;
  float* mlp_b2F = pF + 3072;
  float* ln1gF   = pF + 3456;
  float* ln1bF   = pF + 3840;
  float* ln2gF   = pF + 4224;
  float* ln2bF   = pF + 4608;
  bf16* x2 = (bf16*)(ws + 3559168);
  char* basep = ws + 80629504ULL;
  const size_t avail = (ws_size > 80629504ULL) ? (ws_size - 80629504ULL) : 0;

  // chunk sizes: biggest that fits (fewest launches); M stays a multiple of 64
  int Wc = 128;  // windows per attention chunk (needs Wc*49*1536*2 B)
  { const int cand[5] = {2048, 1024, 512, 256, 128};
    for (int i = 0; i < 5; ++i)
      if ((size_t)cand[i] * 49 * 1536 * 2 <= avail) { Wc = cand[i]; break; } }
  int Rc = 6272;  // rows per MLP chunk (needs Rc*1920*2 B); divides 100352, mult of 64
  { const int cand[5] = {100352, 50176, 25088, 12544, 6272};
    for (int i = 0; i < 5; ++i)
      if ((size_t)cand[i] * 1920 * 2 <= avail) { Rc = cand[i]; break; } }

  // 1) dtype probe
  probe_k<<<1, 256, 0, stream>>>((const u32*)x, flag);

  // 2) canonical params + transposed bf16 weights
  cvt_params_k<<<20, 256, 0, stream>>>(qkv_b, proj_b, mlp_b1, mlp_b2,
                                       ln1_g, ln1_b, ln2_g, ln2_b, pF, flag);
  transpose_k<<<dim3(36, 12), 256, 0, stream>>>(qkv_w, (u16*)qkvwT, 384, 1152, flag);
  transpose_k<<<dim3(12, 12), 256, 0, stream>>>(proj_w, (u16*)projwT, 384, 384, flag);
  transpose_k<<<dim3(48, 12), 256, 0, stream>>>(mlp_w1, (u16*)w1T, 384, 1536, flag);
  transpose_k<<<dim3(12, 48), 256, 0, stream>>>(mlp_w2, (u16*)w2T, 1536, 384, flag);

  // 3) attention path, chunked over windows: x2 = x + proj(attn(LN1(x)))
  for (int c = 0; c < 2048 / Wc; ++c) {
    const int w0 = c * Wc, t0 = w0 * 49, M = Wc * 49;
    const int nM = M / 64;
    bf16* xn   = (bf16*)basep;            // M x 384 (LN1 windowed -> attn_out)
    bf16* qkvb = xn + (size_t)M * 384;    // M x 1152
    ln_kernel<1><<<M / 4, 256, 0, stream>>>(x, ln1gF, ln1bF, (u32*)xn, flag, 1, t0);
    gemm64<0><<<dim3(9 * nM), 256, 0, stream>>>(xn, qkvwT, qkvb, qkv_bF, nullptr, flag,
                                                384, 1152, 384, 0, 9);
    attn_kernel<<<Wc * 3, 256, 0, stream>>>(qkvb, xn);
    gemm64<1><<<dim3(3 * nM), 256, 0, stream>>>(xn, projwT, x2, proj_bF, x, flag,
                                                384, 384, 384, t0, 3);
  }

  // 4) MLP path, chunked over rows: d_out = x2 + mlp(LN2(x2))
  for (int c = 0; c < 100352 / Rc; ++c) {
    const int r0 = c * Rc;
    const int nM = Rc / 64;
    bf16* xn2 = (bf16*)basep;             // Rc x 384
    bf16* hb  = xn2 + (size_t)Rc * 384;   // Rc x 1536
    ln_kernel<0><<<Rc / 4, 256, 0, stream>>>(x2, ln2gF, ln2bF, (u32*)xn2, flag, 0, r0);
    gemm64<2><<<dim3(12 * nM), 256, 0, stream>>>(xn2, w1T, hb, mlp_b1F, nullptr, flag,
                                                 384, 1536, 384, 0, 12);
    gemm64<3><<<dim3(3 * nM), 256, 0, stream>>>(hb, w2T, d_out, mlp_b2F,
                                                x2 + (size_t)r0 * 384, flag,
                                                1536, 384, 1536, r0, 3);
  }
}

// Round 19
// 1075.843 us; speedup vs baseline: 1.2837x; 1.2837x over previous
//
#include <hip/hip_runtime.h>
#include <hip/hip_bf16.h>
#include <cstdint>

typedef __bf16 bf16;
typedef __bf16 bf16x8 __attribute__((ext_vector_type(8)));
typedef float f32x4 __attribute__((ext_vector_type(4)));
typedef unsigned int u32;
typedef unsigned short u16;

#define DEV static __device__ __forceinline__

DEV float bfbits2f(u32 bits) { return __builtin_bit_cast(float, bits << 16); }
DEV u16 f2bfbits(float f) {
  u32 u = __builtin_bit_cast(u32, f);
  u32 r = (u + 0x7fffu + ((u >> 16) & 1u)) >> 16;
  return (u16)r;
}

// ---------------- dtype probe: bf16 data has bf16-exponent-shaped low u16 ----------------
__global__ __launch_bounds__(256) void probe_k(const u32* __restrict__ x, u32* __restrict__ flag) {
  __shared__ int cnt[256];
  int t = threadIdx.x;
  int c = 0;
#pragma unroll
  for (int i = 0; i < 4; ++i) {
    u32 u = x[t * 4 + i];
    u32 e = (u >> 7) & 0xFF;  // exponent field if low u16 were a bf16
    c += (e >= 110 && e <= 140) ? 1 : 0;
  }
  cnt[t] = c;
  __syncthreads();
  for (int s = 128; s > 0; s >>= 1) {
    if (t < s) cnt[t] += cnt[t + s];
    __syncthreads();
  }
  if (t == 0) flag[0] = (cnt[0] > 512) ? 1u : 0u;  // 1 = bf16 inputs, 0 = fp32 inputs
}

// ---------------- small param convert -> canonical f32 (8 vectors, 4992 floats) ----------
__global__ __launch_bounds__(256) void cvt_params_k(const void* p0, const void* p1,
                                                    const void* p2, const void* p3,
                                                    const void* p4, const void* p5,
                                                    const void* p6, const void* p7,
                                                    float* __restrict__ out,
                                                    const u32* __restrict__ flag) {
  int i = blockIdx.x * 256 + threadIdx.x;
  if (i >= 4992) return;
  const int bounds[9] = {0, 1152, 1536, 3072, 3456, 3840, 4224, 4608, 4992};
  const void* ps[8] = {p0, p1, p2, p3, p4, p5, p6, p7};
  int seg = 0;
  while (i >= bounds[seg + 1]) ++seg;
  int off = i - bounds[seg];
  bool isbf = flag[0] != 0;
  out[i] = isbf ? bfbits2f(((const u16*)ps[seg])[off]) : ((const float*)ps[seg])[off];
}

// ---------------- weight transpose+convert ([R][C] f32|bf16 -> [C][R] bf16) --------------
__global__ __launch_bounds__(256) void transpose_k(const void* __restrict__ in,
                                                   u16* __restrict__ out, int R, int Cc,
                                                   const u32* __restrict__ flag) {
  bool isbf = flag[0] != 0;
  __shared__ u16 tile[32][33];
  int bx = blockIdx.x * 32, by = blockIdx.y * 32;
  int tx = threadIdx.x & 31, ty = threadIdx.x >> 5;
#pragma unroll
  for (int i = 0; i < 32; i += 8) {
    size_t idx = (size_t)(by + ty + i) * Cc + bx + tx;
    u16 v = isbf ? ((const u16*)in)[idx] : f2bfbits(((const float*)in)[idx]);
    tile[ty + i][tx] = v;
  }
  __syncthreads();
#pragma unroll
  for (int i = 0; i < 32; i += 8)
    out[(size_t)(bx + ty + i) * R + by + tx] = tile[tx][ty + i];
}

// ---------------- LayerNorm over C=384, chunk-local bf16 output ----------------
// RAWSRC=1: input is raw d_in x (flag-aware f32|bf16); RAWSRC=0: internal bf16.
// windowed=1: out row = windowpartition(t) - t0 ; windowed=0: out row = t - t0
template <int RAWSRC>
__global__ __launch_bounds__(256) void ln_kernel(const void* __restrict__ xv,
                                                 const float* __restrict__ g,
                                                 const float* __restrict__ b,
                                                 u32* __restrict__ out,
                                                 const u32* __restrict__ flag,
                                                 int windowed, int t0) {
  const int t = t0 + blockIdx.x * 4 + (threadIdx.x >> 6);
  const int lane = threadIdx.x & 63;
  const int e0 = lane * 6;
  float f[6];
  if (RAWSRC) {
    if (flag[0] != 0) {
      const u16* xb = (const u16*)xv + (size_t)t * 384 + e0;
#pragma unroll
      for (int j = 0; j < 6; ++j) f[j] = bfbits2f(xb[j]);
    } else {
      const float* xf = (const float*)xv + (size_t)t * 384 + e0;
#pragma unroll
      for (int j = 0; j < 6; ++j) f[j] = xf[j];
    }
  } else {
    const u32* xr = (const u32*)xv + (size_t)t * 192 + lane * 3;
#pragma unroll
    for (int j = 0; j < 3; ++j) {
      u32 u = xr[j];
      f[2 * j] = bfbits2f(u & 0xffff);
      f[2 * j + 1] = bfbits2f(u >> 16);
    }
  }
  float s = 0.f, q = 0.f;
#pragma unroll
  for (int j = 0; j < 6; ++j) { s += f[j]; q += f[j] * f[j]; }
#pragma unroll
  for (int o = 1; o < 64; o <<= 1) { s += __shfl_xor(s, o); q += __shfl_xor(q, o); }
  float mean = s * (1.0f / 384.0f);
  float var = q * (1.0f / 384.0f) - mean * mean;
  float rstd = rsqrtf(var + 1e-5f);
  int orow;
  if (windowed) {
    int bb = t / 3136, rem = t % 3136;
    int hh = rem / 56, ww = rem % 56;
    orow = (bb * 64 + (hh / 7) * 8 + (ww / 7)) * 49 + (hh % 7) * 7 + (ww % 7) - t0;
  } else {
    orow = t - t0;
  }
  u32* orp = out + (size_t)orow * 192 + lane * 3;
#pragma unroll
  for (int j = 0; j < 3; ++j) {
    float ye = (f[2 * j] - mean) * rstd * g[e0 + 2 * j] + b[e0 + 2 * j];
    float yo = (f[2 * j + 1] - mean) * rstd * g[e0 + 2 * j + 1] + b[e0 + 2 * j + 1];
    orp[j] = (u32)f2bfbits(ye) | ((u32)f2bfbits(yo) << 16);
  }
}

// ---------------- 128x128 GEMM: R15 geometry + dbuf + counted vmcnt (T3+T4) --------------
// The untested matrix cell: BN=128 conflict-free T2 geometry (R15, 894us best) with
// double-buffered global_load_lds and counted s_waitcnt vmcnt(8) across RAW s_barrier
// (no drain). Tile t+1's 8 loads/thread stay in flight while tile t computes.
// LDS 64KB -> 2 blocks/CU; counted-vmcnt supplies the pipelining lost to occupancy.
// MODE 0: C(bf16) = A*B + bias                          (qkv)
// MODE 1: C(bf16)[raw(rowOff+row)] = A*B + bias + res   (proj; res = raw x, flag-aware)
// MODE 2: C(bf16) = gelu(A*B + bias)                    (mlp1)
// MODE 3: C(d_out + rowOff, flag-aware) = A*B + bias + res(bf16 chunk-local)  (mlp2)
template <int MODE>
__global__ __launch_bounds__(256, 2) void gemm128(const bf16* __restrict__ A,
                                                  const bf16* __restrict__ BT,
                                                  void* __restrict__ Cv,
                                                  const float* __restrict__ bias,
                                                  const void* __restrict__ resv,
                                                  const u32* __restrict__ flag,
                                                  int ldA, int ldC, int K, int rowOff,
                                                  int nN) {
  // XCD-chunk swizzle (bijective for any nwg; m204)
  const int nwg = (int)gridDim.x;
  const int bid = (int)blockIdx.x;
  const int q = nwg >> 3, r = nwg & 7;
  const int xcd = bid & 7, lid = bid >> 3;
  const int wg = (xcd < r ? xcd * (q + 1) : r * (q + 1) + (xcd - r) * q) + lid;
  const int tN = wg % nN, tM = wg / nN;

  const int tid = threadIdx.x;
  const int lane = tid & 63, wave = tid >> 6;
  const int wr = wave >> 1, wc = wave & 1;
  const int li = lane & 15, gq = lane >> 4;
  const bool isbf = flag[0] != 0;

  __shared__ bf16 As[2][128 * 64];   // 2 x 16KB
  __shared__ bf16 Bs[2][128 * 64];   // 2 x 16KB

  f32x4 acc[4][4] = {};

  const bf16* aTile = A + (size_t)tM * 128 * ldA;
  const bf16* bTile = BT + (size_t)tN * 128 * K;

  // 8 global_load_lds per thread per stage; T2 pre-swizzled global source granule
  auto stage = [&](int buf, int kk) {
#pragma unroll
    for (int i = 0; i < 4; ++i) {
      int c = i * 256 + tid;
      int row = c >> 3, col8 = ((c & 7) ^ (row & 7)) << 3;
      __builtin_amdgcn_global_load_lds(
          (const __attribute__((address_space(1))) void*)(aTile + (size_t)row * ldA + kk + col8),
          (__attribute__((address_space(3))) void*)(As[buf] + (size_t)c * 8), 16, 0, 0);
      __builtin_amdgcn_global_load_lds(
          (const __attribute__((address_space(1))) void*)(bTile + (size_t)row * K + kk + col8),
          (__attribute__((address_space(3))) void*)(Bs[buf] + (size_t)c * 8), 16, 0, 0);
    }
  };

  const int nt = K >> 6;
  stage(0, 0);
  for (int t = 0; t < nt; ++t) {
    const int cur = t & 1;
    if (t + 1 < nt) {
      stage(cur ^ 1, (t + 1) << 6);   // 8 more loads in flight (16 total)
      asm volatile("s_waitcnt vmcnt(8)" ::: "memory");  // tile t's 8 landed; t+1's stay
    } else {
      asm volatile("s_waitcnt vmcnt(0)" ::: "memory");
    }
    __builtin_amdgcn_sched_barrier(0);
    __builtin_amdgcn_s_barrier();     // raw barrier: no drain of t+1's loads
    __builtin_amdgcn_sched_barrier(0);
#pragma unroll
    for (int ks = 0; ks < 64; ks += 32) {
      bf16x8 af[4], bfr[4];
#pragma unroll
      for (int m = 0; m < 4; ++m) {
        int arow = wr * 64 + m * 16 + li;
        af[m] = *(const bf16x8*)(As[cur] + arow * 64 + ((((ks >> 3) + gq) ^ (arow & 7)) << 3));
      }
#pragma unroll
      for (int n = 0; n < 4; ++n) {
        int brow = wc * 64 + n * 16 + li;
        bfr[n] = *(const bf16x8*)(Bs[cur] + brow * 64 + ((((ks >> 3) + gq) ^ (brow & 7)) << 3));
      }
#pragma unroll
      for (int m = 0; m < 4; ++m)
#pragma unroll
        for (int n = 0; n < 4; ++n)
          acc[m][n] = __builtin_amdgcn_mfma_f32_16x16x32_bf16(af[m], bfr[n], acc[m][n], 0, 0, 0);
    }
    __builtin_amdgcn_sched_barrier(0);
    __builtin_amdgcn_s_barrier();     // all waves done with buf[cur] before next stage hits it
    __builtin_amdgcn_sched_barrier(0);
  }

#pragma unroll
  for (int m = 0; m < 4; ++m) {
#pragma unroll
    for (int r2 = 0; r2 < 4; ++r2) {
      int row = tM * 128 + wr * 64 + m * 16 + gq * 4 + r2;
      size_t crow;
      if (MODE == 1) {
        int gg = rowOff + row;
        int win = gg / 49, n = gg % 49;
        int bb = win >> 6, wi = win & 63;
        int hh = (wi >> 3) * 7 + n / 7;
        int ww = (wi & 7) * 7 + n % 7;
        crow = (size_t)(bb * 3136 + hh * 56 + ww);
      } else {
        crow = (size_t)row;
      }
#pragma unroll
      for (int n = 0; n < 4; ++n) {
        int col = tN * 128 + wc * 64 + n * 16 + li;
        size_t idx = crow * (size_t)ldC + col;
        float v = acc[m][n][r2] + bias[col];
        if (MODE == 2) v = 0.5f * v * (1.0f + erff(v * 0.70710678118654752f));
        if (MODE == 1)
          v += isbf ? bfbits2f(((const u16*)resv)[idx]) : ((const float*)resv)[idx];
        if (MODE == 3) v += bfbits2f(((const u16*)resv)[idx]);
        if (MODE == 3) {
          size_t oidx = idx + (size_t)rowOff * 384;
          if (isbf) ((u16*)Cv)[oidx] = f2bfbits(v);
          else ((float*)Cv)[oidx] = v;
        } else {
          ((u16*)Cv)[idx] = f2bfbits(v);
        }
      }
    }
  }
}

// ---------------- window attention: one wave per (window, head) ----------------
// qkv rows are window-ordered [nWin*49][1152] bf16; cols = which*384 + head*32 + d
__global__ __launch_bounds__(256, 2) void attn_kernel(const bf16* __restrict__ qkv,
                                                      bf16* __restrict__ out) {
  __shared__ bf16 smem[4 * 6912];  // per wave: P[64][72] + VT[32][72]
  const int wave = threadIdx.x >> 6;
  const int lane = threadIdx.x & 63;
  const int unit = blockIdx.x * 4 + wave;
  const int win = unit / 12, head = unit % 12;
  bf16* P = smem + wave * 6912;
  bf16* VT = P + 64 * 72;

  const size_t base = (size_t)win * 49 * 1152 + head * 32;
  const bf16* Qp = qkv + base;
  const bf16* Kp = qkv + base + 384;
  const bf16* Vp = qkv + base + 768;

  const int gq = lane >> 4, li = lane & 15;

  // stage V^T into LDS (zero-pad m in [49,64))
  {
    int d = lane & 31, half = lane >> 5;
#pragma unroll
    for (int i = 0; i < 32; ++i) {
      int m = i * 2 + half;
      bf16 v = (m < 49) ? Vp[(size_t)m * 1152 + d] : (bf16)0.0f;
      VT[d * 72 + m] = v;
    }
  }

  // S = Q K^T (49 padded to 64; rows clamped)
  f32x4 s[4][4] = {};
  bf16x8 qf[4], kf[4];
#pragma unroll
  for (int i = 0; i < 4; ++i) {
    int qr = i * 16 + li; if (qr > 48) qr = 48;
    qf[i] = *(const bf16x8*)(Qp + (size_t)qr * 1152 + gq * 8);
    kf[i] = *(const bf16x8*)(Kp + (size_t)qr * 1152 + gq * 8);
  }
#pragma unroll
  for (int i = 0; i < 4; ++i)
#pragma unroll
    for (int j = 0; j < 4; ++j)
      s[i][j] = __builtin_amdgcn_mfma_f32_16x16x32_bf16(qf[i], kf[j], s[i][j], 0, 0, 0);

  __syncthreads();  // V^T staging visible before PV reads

  // softmax per row n = i*16 + gq*4 + r; cols m = tj*16 + li (mask m>=49: tj==3, li>=1)
  const float scale = 0.17677669529663687f;  // 1/sqrt(32)
#pragma unroll
  for (int i = 0; i < 4; ++i) {
#pragma unroll
    for (int r = 0; r < 4; ++r) {
      float v0 = s[i][0][r] * scale, v1 = s[i][1][r] * scale;
      float v2 = s[i][2][r] * scale, v3 = s[i][3][r] * scale;
      if (li >= 1) v3 = -1e30f;
      float mx = fmaxf(fmaxf(v0, v1), fmaxf(v2, v3));
#pragma unroll
      for (int o = 1; o < 16; o <<= 1) mx = fmaxf(mx, __shfl_xor(mx, o));
      v0 = __expf(v0 - mx); v1 = __expf(v1 - mx);
      v2 = __expf(v2 - mx); v3 = __expf(v3 - mx);
      float sum = v0 + v1 + v2 + v3;
#pragma unroll
      for (int o = 1; o < 16; o <<= 1) sum += __shfl_xor(sum, o);
      float inv = 1.0f / sum;
      int n = i * 16 + gq * 4 + r;
      P[n * 72 + li]      = (bf16)(v0 * inv);
      P[n * 72 + 16 + li] = (bf16)(v1 * inv);
      P[n * 72 + 32 + li] = (bf16)(v2 * inv);
      P[n * 72 + 48 + li] = (bf16)(v3 * inv);
    }
  }

  __syncthreads();  // P writes visible before PV reads

  // O = P * V
  f32x4 o[4][2] = {};
#pragma unroll
  for (int ms = 0; ms < 2; ++ms) {
    bf16x8 pf[4], vf[2];
#pragma unroll
    for (int i = 0; i < 4; ++i)
      pf[i] = *(const bf16x8*)(P + (i * 16 + li) * 72 + ms * 32 + gq * 8);
#pragma unroll
    for (int dt = 0; dt < 2; ++dt)
      vf[dt] = *(const bf16x8*)(VT + (dt * 16 + li) * 72 + ms * 32 + gq * 8);
#pragma unroll
    for (int i = 0; i < 4; ++i)
#pragma unroll
      for (int dt = 0; dt < 2; ++dt)
        o[i][dt] = __builtin_amdgcn_mfma_f32_16x16x32_bf16(pf[i], vf[dt], o[i][dt], 0, 0, 0);
  }

#pragma unroll
  for (int i = 0; i < 4; ++i) {
#pragma unroll
    for (int r = 0; r < 4; ++r) {
      int n = i * 16 + gq * 4 + r;
      if (n < 49) {
#pragma unroll
        for (int dt = 0; dt < 2; ++dt) {
          int d = dt * 16 + li;
          out[((size_t)win * 49 + n) * 384 + head * 32 + d] = (bf16)o[i][dt][r];
        }
      }
    }
  }
}

// ---------------- host ----------------
extern "C" void kernel_launch(void* const* d_in, const int* in_sizes, int n_in,
                              void* d_out, int out_size, void* d_ws, size_t ws_size,
                              hipStream_t stream) {
  const void* x      = d_in[0];
  const void* ln1_g  = d_in[1];
  const void* ln1_b  = d_in[2];
  const void* qkv_w  = d_in[3];
  const void* qkv_b  = d_in[4];
  const void* proj_w = d_in[5];
  const void* proj_b = d_in[6];
  const void* ln2_g  = d_in[7];
  const void* ln2_b  = d_in[8];
  const void* mlp_w1 = d_in[9];
  const void* mlp_b1 = d_in[10];
  const void* mlp_w2 = d_in[11];
  const void* mlp_b2 = d_in[12];

  // ws layout (bytes):
  //   0        flag (u32, padded to 256)
  //   256      transposed bf16 weights (3,538,944)
  //   3539200  canonical f32 params (4992 floats)
  //   3559168  x2 internal bf16 (77,070,336)
  //   80629504 phase region (adaptive chunks)
  char* ws = (char*)d_ws;
  u32* flag = (u32*)ws;
  bf16* qkvwT  = (bf16*)(ws + 256);
  bf16* projwT = qkvwT + 1152 * 384;
  bf16* w1T    = projwT + 384 * 384;
  bf16* w2T    = w1T + 1536 * 384;
  float* pF    = (float*)(ws + 3539200);
  float* qkv_bF  = pF;
  float* proj_bF = pF + 1152;
  float* mlp_b1F = pF + 1536;
  float* mlp_b2F = pF + 3072;
  float* ln1gF   = pF + 3456;
  float* ln1bF   = pF + 3840;
  float* ln2gF   = pF + 4224;
  float* ln2bF   = pF + 4608;
  bf16* x2 = (bf16*)(ws + 3559168);
  char* basep = ws + 80629504ULL;
  const size_t avail = (ws_size > 80629504ULL) ? (ws_size - 80629504ULL) : 0;

  // chunk sizes: biggest that fits (fewest launches); M multiple of 128
  int Wc = 128;  // windows per attention chunk (needs Wc*49*1536*2 B)
  { const int cand[5] = {2048, 1024, 512, 256, 128};
    for (int i = 0; i < 5; ++i)
      if ((size_t)cand[i] * 49 * 1536 * 2 <= avail) { Wc = cand[i]; break; } }
  int Rc = 6272;  // rows per MLP chunk (needs Rc*1920*2 B); divides 100352, mult of 128
  { const int cand[5] = {100352, 50176, 25088, 12544, 6272};
    for (int i = 0; i < 5; ++i)
      if ((size_t)cand[i] * 1920 * 2 <= avail) { Rc = cand[i]; break; } }

  // 1) dtype probe
  probe_k<<<1, 256, 0, stream>>>((const u32*)x, flag);

  // 2) canonical params + transposed bf16 weights
  cvt_params_k<<<20, 256, 0, stream>>>(qkv_b, proj_b, mlp_b1, mlp_b2,
                                       ln1_g, ln1_b, ln2_g, ln2_b, pF, flag);
  transpose_k<<<dim3(36, 12), 256, 0, stream>>>(qkv_w, (u16*)qkvwT, 384, 1152, flag);
  transpose_k<<<dim3(12, 12), 256, 0, stream>>>(proj_w, (u16*)projwT, 384, 384, flag);
  transpose_k<<<dim3(48, 12), 256, 0, stream>>>(mlp_w1, (u16*)w1T, 384, 1536, flag);
  transpose_k<<<dim3(12, 48), 256, 0, stream>>>(mlp_w2, (u16*)w2T, 1536, 384, flag);

  // 3) attention path, chunked over windows: x2 = x + proj(attn(LN1(x)))
  for (int c = 0; c < 2048 / Wc; ++c) {
    const int w0 = c * Wc, t0 = w0 * 49, M = Wc * 49;
    const int nM = M / 128;
    bf16* xn   = (bf16*)basep;            // M x 384 (LN1 windowed -> attn_out)
    bf16* qkvb = xn + (size_t)M * 384;    // M x 1152
    ln_kernel<1><<<M / 4, 256, 0, stream>>>(x, ln1gF, ln1bF, (u32*)xn, flag, 1, t0);
    gemm128<0><<<dim3(9 * nM), 256, 0, stream>>>(xn, qkvwT, qkvb, qkv_bF, nullptr, flag,
                                                 384, 1152, 384, 0, 9);
    attn_kernel<<<Wc * 3, 256, 0, stream>>>(qkvb, xn);
    gemm128<1><<<dim3(3 * nM), 256, 0, stream>>>(xn, projwT, x2, proj_bF, x, flag,
                                                 384, 384, 384, t0, 3);
  }

  // 4) MLP path, chunked over rows: d_out = x2 + mlp(LN2(x2))
  for (int c = 0; c < 100352 / Rc; ++c) {
    const int r0 = c * Rc;
    const int nM = Rc / 128;
    bf16* xn2 = (bf16*)basep;             // Rc x 384
    bf16* hb  = xn2 + (size_t)Rc * 384;   // Rc x 1536
    ln_kernel<0><<<Rc / 4, 256, 0, stream>>>(x2, ln2gF, ln2bF, (u32*)xn2, flag, 0, r0);
    gemm128<2><<<dim3(12 * nM), 256, 0, stream>>>(xn2, w1T, hb, mlp_b1F, nullptr, flag,
                                                  384, 1536, 384, 0, 12);
    gemm128<3><<<dim3(3 * nM), 256, 0, stream>>>(hb, w2T, d_out, mlp_b2F,
                                                 x2 + (size_t)r0 * 384, flag,
                                                 1536, 384, 1536, r0, 3);
  }
}

// Round 20
// 889.090 us; speedup vs baseline: 1.5534x; 1.2100x over previous
//
#include <hip/hip_runtime.h>
#include <hip/hip_bf16.h>
#include <cstdint>

typedef __bf16 bf16;
typedef __bf16 bf16x8 __attribute__((ext_vector_type(8)));
typedef float f32x4 __attribute__((ext_vector_type(4)));
typedef unsigned int u32;
typedef unsigned short u16;

#define DEV static __device__ __forceinline__

DEV float bfbits2f(u32 bits) { return __builtin_bit_cast(float, bits << 16); }
DEV u16 f2bfbits(float f) {
  u32 u = __builtin_bit_cast(u32, f);
  u32 r = (u + 0x7fffu + ((u >> 16) & 1u)) >> 16;
  return (u16)r;
}

// ---------------- dtype probe: bf16 data has bf16-exponent-shaped low u16 ----------------
__global__ __launch_bounds__(256) void probe_k(const u32* __restrict__ x, u32* __restrict__ flag) {
  __shared__ int cnt[256];
  int t = threadIdx.x;
  int c = 0;
#pragma unroll
  for (int i = 0; i < 4; ++i) {
    u32 u = x[t * 4 + i];
    u32 e = (u >> 7) & 0xFF;  // exponent field if low u16 were a bf16
    c += (e >= 110 && e <= 140) ? 1 : 0;
  }
  cnt[t] = c;
  __syncthreads();
  for (int s = 128; s > 0; s >>= 1) {
    if (t < s) cnt[t] += cnt[t + s];
    __syncthreads();
  }
  if (t == 0) flag[0] = (cnt[0] > 512) ? 1u : 0u;  // 1 = bf16 inputs, 0 = fp32 inputs
}

// ---------------- small param convert -> canonical f32 (8 vectors, 4992 floats) ----------
__global__ __launch_bounds__(256) void cvt_params_k(const void* p0, const void* p1,
                                                    const void* p2, const void* p3,
                                                    const void* p4, const void* p5,
                                                    const void* p6, const void* p7,
                                                    float* __restrict__ out,
                                                    const u32* __restrict__ flag) {
  int i = blockIdx.x * 256 + threadIdx.x;
  if (i >= 4992) return;
  const int bounds[9] = {0, 1152, 1536, 3072, 3456, 3840, 4224, 4608, 4992};
  const void* ps[8] = {p0, p1, p2, p3, p4, p5, p6, p7};
  int seg = 0;
  while (i >= bounds[seg + 1]) ++seg;
  int off = i - bounds[seg];
  bool isbf = flag[0] != 0;
  out[i] = isbf ? bfbits2f(((const u16*)ps[seg])[off]) : ((const float*)ps[seg])[off];
}

// ---------------- weight transpose+convert ([R][C] f32|bf16 -> [C][R] bf16) --------------
__global__ __launch_bounds__(256) void transpose_k(const void* __restrict__ in,
                                                   u16* __restrict__ out, int R, int Cc,
                                                   const u32* __restrict__ flag) {
  bool isbf = flag[0] != 0;
  __shared__ u16 tile[32][33];
  int bx = blockIdx.x * 32, by = blockIdx.y * 32;
  int tx = threadIdx.x & 31, ty = threadIdx.x >> 5;
#pragma unroll
  for (int i = 0; i < 32; i += 8) {
    size_t idx = (size_t)(by + ty + i) * Cc + bx + tx;
    u16 v = isbf ? ((const u16*)in)[idx] : f2bfbits(((const float*)in)[idx]);
    tile[ty + i][tx] = v;
  }
  __syncthreads();
#pragma unroll
  for (int i = 0; i < 32; i += 8)
    out[(size_t)(bx + ty + i) * R + by + tx] = tile[tx][ty + i];
}

// ---------------- LayerNorm over C=384, chunk-local bf16 output ----------------
// RAWSRC=1: input is raw d_in x (flag-aware f32|bf16); RAWSRC=0: internal bf16.
// windowed=1: out row = windowpartition(t) - t0 ; windowed=0: out row = t - t0
template <int RAWSRC>
__global__ __launch_bounds__(256) void ln_kernel(const void* __restrict__ xv,
                                                 const float* __restrict__ g,
                                                 const float* __restrict__ b,
                                                 u32* __restrict__ out,
                                                 const u32* __restrict__ flag,
                                                 int windowed, int t0) {
  const int t = t0 + blockIdx.x * 4 + (threadIdx.x >> 6);
  const int lane = threadIdx.x & 63;
  const int e0 = lane * 6;
  float f[6];
  if (RAWSRC) {
    if (flag[0] != 0) {
      const u16* xb = (const u16*)xv + (size_t)t * 384 + e0;
#pragma unroll
      for (int j = 0; j < 6; ++j) f[j] = bfbits2f(xb[j]);
    } else {
      const float* xf = (const float*)xv + (size_t)t * 384 + e0;
#pragma unroll
      for (int j = 0; j < 6; ++j) f[j] = xf[j];
    }
  } else {
    const u32* xr = (const u32*)xv + (size_t)t * 192 + lane * 3;
#pragma unroll
    for (int j = 0; j < 3; ++j) {
      u32 u = xr[j];
      f[2 * j] = bfbits2f(u & 0xffff);
      f[2 * j + 1] = bfbits2f(u >> 16);
    }
  }
  float s = 0.f, q = 0.f;
#pragma unroll
  for (int j = 0; j < 6; ++j) { s += f[j]; q += f[j] * f[j]; }
#pragma unroll
  for (int o = 1; o < 64; o <<= 1) { s += __shfl_xor(s, o); q += __shfl_xor(q, o); }
  float mean = s * (1.0f / 384.0f);
  float var = q * (1.0f / 384.0f) - mean * mean;
  float rstd = rsqrtf(var + 1e-5f);
  int orow;
  if (windowed) {
    int bb = t / 3136, rem = t % 3136;
    int hh = rem / 56, ww = rem % 56;
    orow = (bb * 64 + (hh / 7) * 8 + (ww / 7)) * 49 + (hh % 7) * 7 + (ww % 7) - t0;
  } else {
    orow = t - t0;
  }
  u32* orp = out + (size_t)orow * 192 + lane * 3;
#pragma unroll
  for (int j = 0; j < 3; ++j) {
    float ye = (f[2 * j] - mean) * rstd * g[e0 + 2 * j] + b[e0 + 2 * j];
    float yo = (f[2 * j + 1] - mean) * rstd * g[e0 + 2 * j + 1] + b[e0 + 2 * j + 1];
    orp[j] = (u32)f2bfbits(ye) | ((u32)f2bfbits(yo) << 16);
  }
}

// ---------------- m97-style 128x128 MFMA GEMM, BK=64 + T2 XOR-swizzle --------------------
// Best-known configuration (R15, 894us): single-buffered global_load_lds, __syncthreads,
// bounds (256,4), 1-D bijective XCD swizzle with tN fastest, and the T2 swizzle pair
// (pre-permuted global source granule + matching XOR on ds_read) -> 0 bank conflicts.
// MODE 0: C(bf16) = A*B + bias                          (qkv)
// MODE 1: C(bf16)[raw(rowOff+row)] = A*B + bias + res   (proj; res = raw x, flag-aware)
// MODE 2: C(bf16) = gelu(A*B + bias)                    (mlp1)
// MODE 3: C(d_out + rowOff, flag-aware) = A*B + bias + res(bf16 chunk-local)  (mlp2)
template <int MODE>
__global__ __launch_bounds__(256, 4) void gemm128(const bf16* __restrict__ A,
                                                  const bf16* __restrict__ BT,
                                                  void* __restrict__ Cv,
                                                  const float* __restrict__ bias,
                                                  const void* __restrict__ resv,
                                                  const u32* __restrict__ flag,
                                                  int ldA, int ldC, int K, int rowOff,
                                                  int nN) {
  // XCD-chunk swizzle (bijective for any nwg; m204)
  const int nwg = (int)gridDim.x;
  const int bid = (int)blockIdx.x;
  const int q = nwg >> 3, r = nwg & 7;
  const int xcd = bid & 7, lid = bid >> 3;
  const int wg = (xcd < r ? xcd * (q + 1) : r * (q + 1) + (xcd - r) * q) + lid;
  const int tN = wg % nN, tM = wg / nN;

  const int tid = threadIdx.x;
  const int lane = tid & 63, wave = tid >> 6;
  const int wr = wave >> 1, wc = wave & 1;
  const int li = lane & 15, gq = lane >> 4;
  const bool isbf = flag[0] != 0;

  __shared__ bf16 As[128 * 64];
  __shared__ bf16 Bs[128 * 64];

  f32x4 acc[4][4] = {};

  const bf16* aTile = A + (size_t)tM * 128 * ldA;
  const bf16* bTile = BT + (size_t)tN * 128 * K;

  for (int k0 = 0; k0 < K; k0 += 64) {
#pragma unroll
    for (int i = 0; i < 4; ++i) {
      int c = i * 256 + tid;
      int row = c >> 3, col8 = ((c & 7) ^ (row & 7)) << 3;  // T2: pre-swizzled source
      __builtin_amdgcn_global_load_lds(
          (const __attribute__((address_space(1))) void*)(aTile + (size_t)row * ldA + k0 + col8),
          (__attribute__((address_space(3))) void*)(As + (size_t)c * 8), 16, 0, 0);
      __builtin_amdgcn_global_load_lds(
          (const __attribute__((address_space(1))) void*)(bTile + (size_t)row * K + k0 + col8),
          (__attribute__((address_space(3))) void*)(Bs + (size_t)c * 8), 16, 0, 0);
    }
    __syncthreads();
#pragma unroll
    for (int ks = 0; ks < 64; ks += 32) {
      bf16x8 af[4], bfr[4];
#pragma unroll
      for (int m = 0; m < 4; ++m) {
        int arow = wr * 64 + m * 16 + li;
        af[m] = *(const bf16x8*)(As + arow * 64 + ((((ks >> 3) + gq) ^ (arow & 7)) << 3));
      }
#pragma unroll
      for (int n = 0; n < 4; ++n) {
        int brow = wc * 64 + n * 16 + li;
        bfr[n] = *(const bf16x8*)(Bs + brow * 64 + ((((ks >> 3) + gq) ^ (brow & 7)) << 3));
      }
#pragma unroll
      for (int m = 0; m < 4; ++m)
#pragma unroll
        for (int n = 0; n < 4; ++n)
          acc[m][n] = __builtin_amdgcn_mfma_f32_16x16x32_bf16(af[m], bfr[n], acc[m][n], 0, 0, 0);
    }
    __syncthreads();
  }

#pragma unroll
  for (int m = 0; m < 4; ++m) {
#pragma unroll
    for (int r2 = 0; r2 < 4; ++r2) {
      int row = tM * 128 + wr * 64 + m * 16 + gq * 4 + r2;
      size_t crow;
      if (MODE == 1) {
        int gg = rowOff + row;
        int win = gg / 49, n = gg % 49;
        int bb = win >> 6, wi = win & 63;
        int hh = (wi >> 3) * 7 + n / 7;
        int ww = (wi & 7) * 7 + n % 7;
        crow = (size_t)(bb * 3136 + hh * 56 + ww);
      } else {
        crow = (size_t)row;
      }
#pragma unroll
      for (int n = 0; n < 4; ++n) {
        int col = tN * 128 + wc * 64 + n * 16 + li;
        size_t idx = crow * (size_t)ldC + col;
        float v = acc[m][n][r2] + bias[col];
        if (MODE == 2) v = 0.5f * v * (1.0f + erff(v * 0.70710678118654752f));
        if (MODE == 1)
          v += isbf ? bfbits2f(((const u16*)resv)[idx]) : ((const float*)resv)[idx];
        if (MODE == 3) v += bfbits2f(((const u16*)resv)[idx]);
        if (MODE == 3) {
          size_t oidx = idx + (size_t)rowOff * 384;
          if (isbf) ((u16*)Cv)[oidx] = f2bfbits(v);
          else ((float*)Cv)[oidx] = v;
        } else {
          ((u16*)Cv)[idx] = f2bfbits(v);
        }
      }
    }
  }
}

// ---------------- window attention: one wave per (window, head) ----------------
// qkv rows are window-ordered [nWin*49][1152] bf16; cols = which*384 + head*32 + d
__global__ __launch_bounds__(256, 2) void attn_kernel(const bf16* __restrict__ qkv,
                                                      bf16* __restrict__ out) {
  __shared__ bf16 smem[4 * 6912];  // per wave: P[64][72] + VT[32][72]
  const int wave = threadIdx.x >> 6;
  const int lane = threadIdx.x & 63;
  const int unit = blockIdx.x * 4 + wave;
  const int win = unit / 12, head = unit % 12;
  bf16* P = smem + wave * 6912;
  bf16* VT = P + 64 * 72;

  const size_t base = (size_t)win * 49 * 1152 + head * 32;
  const bf16* Qp = qkv + base;
  const bf16* Kp = qkv + base + 384;
  const bf16* Vp = qkv + base + 768;

  const int gq = lane >> 4, li = lane & 15;

  // stage V^T into LDS (zero-pad m in [49,64))
  {
    int d = lane & 31, half = lane >> 5;
#pragma unroll
    for (int i = 0; i < 32; ++i) {
      int m = i * 2 + half;
      bf16 v = (m < 49) ? Vp[(size_t)m * 1152 + d] : (bf16)0.0f;
      VT[d * 72 + m] = v;
    }
  }

  // S = Q K^T (49 padded to 64; rows clamped)
  f32x4 s[4][4] = {};
  bf16x8 qf[4], kf[4];
#pragma unroll
  for (int i = 0; i < 4; ++i) {
    int qr = i * 16 + li; if (qr > 48) qr = 48;
    qf[i] = *(const bf16x8*)(Qp + (size_t)qr * 1152 + gq * 8);
    kf[i] = *(const bf16x8*)(Kp + (size_t)qr * 1152 + gq * 8);
  }
#pragma unroll
  for (int i = 0; i < 4; ++i)
#pragma unroll
    for (int j = 0; j < 4; ++j)
      s[i][j] = __builtin_amdgcn_mfma_f32_16x16x32_bf16(qf[i], kf[j], s[i][j], 0, 0, 0);

  __syncthreads();  // V^T staging visible before PV reads

  // softmax per row n = i*16 + gq*4 + r; cols m = tj*16 + li (mask m>=49: tj==3, li>=1)
  const float scale = 0.17677669529663687f;  // 1/sqrt(32)
#pragma unroll
  for (int i = 0; i < 4; ++i) {
#pragma unroll
    for (int r = 0; r < 4; ++r) {
      float v0 = s[i][0][r] * scale, v1 = s[i][1][r] * scale;
      float v2 = s[i][2][r] * scale, v3 = s[i][3][r] * scale;
      if (li >= 1) v3 = -1e30f;
      float mx = fmaxf(fmaxf(v0, v1), fmaxf(v2, v3));
#pragma unroll
      for (int o = 1; o < 16; o <<= 1) mx = fmaxf(mx, __shfl_xor(mx, o));
      v0 = __expf(v0 - mx); v1 = __expf(v1 - mx);
      v2 = __expf(v2 - mx); v3 = __expf(v3 - mx);
      float sum = v0 + v1 + v2 + v3;
#pragma unroll
      for (int o = 1; o < 16; o <<= 1) sum += __shfl_xor(sum, o);
      float inv = 1.0f / sum;
      int n = i * 16 + gq * 4 + r;
      P[n * 72 + li]      = (bf16)(v0 * inv);
      P[n * 72 + 16 + li] = (bf16)(v1 * inv);
      P[n * 72 + 32 + li] = (bf16)(v2 * inv);
      P[n * 72 + 48 + li] = (bf16)(v3 * inv);
    }
  }

  __syncthreads();  // P writes visible before PV reads

  // O = P * V
  f32x4 o[4][2] = {};
#pragma unroll
  for (int ms = 0; ms < 2; ++ms) {
    bf16x8 pf[4], vf[2];
#pragma unroll
    for (int i = 0; i < 4; ++i)
      pf[i] = *(const bf16x8*)(P + (i * 16 + li) * 72 + ms * 32 + gq * 8);
#pragma unroll
    for (int dt = 0; dt < 2; ++dt)
      vf[dt] = *(const bf16x8*)(VT + (dt * 16 + li) * 72 + ms * 32 + gq * 8);
#pragma unroll
    for (int i = 0; i < 4; ++i)
#pragma unroll
      for (int dt = 0; dt < 2; ++dt)
        o[i][dt] = __builtin_amdgcn_mfma_f32_16x16x32_bf16(pf[i], vf[dt], o[i][dt], 0, 0, 0);
  }

#pragma unroll
  for (int i = 0; i < 4; ++i) {
#pragma unroll
    for (int r = 0; r < 4; ++r) {
      int n = i * 16 + gq * 4 + r;
      if (n < 49) {
#pragma unroll
        for (int dt = 0; dt < 2; ++dt) {
          int d = dt * 16 + li;
          out[((size_t)win * 49 + n) * 384 + head * 32 + d] = (bf16)o[i][dt][r];
        }
      }
    }
  }
}

// ---------------- host ----------------
extern "C" void kernel_launch(void* const* d_in, const int* in_sizes, int n_in,
                              void* d_out, int out_size, void* d_ws, size_t ws_size,
                              hipStream_t stream) {
  const void* x      = d_in[0];
  const void* ln1_g  = d_in[1];
  const void* ln1_b  = d_in[2];
  const void* qkv_w  = d_in[3];
  const void* qkv_b  = d_in[4];
  const void* proj_w = d_in[5];
  const void* proj_b = d_in[6];
  const void* ln2_g  = d_in[7];
  const void* ln2_b  = d_in[8];
  const void* mlp_w1 = d_in[9];
  const void* mlp_b1 = d_in[10];
  const void* mlp_w2 = d_in[11];
  const void* mlp_b2 = d_in[12];

  // ws layout (bytes):
  //   0        flag (u32, padded to 256)
  //   256      transposed bf16 weights (3,538,944)
  //   3539200  canonical f32 params (4992 floats)
  //   3559168  x2 internal bf16 (77,070,336)
  //   80629504 phase region (adaptive chunks)
  char* ws = (char*)d_ws;
  u32* flag = (u32*)ws;
  bf16* qkvwT  = (bf16*)(ws + 256);
  bf16* projwT = qkvwT + 1152 * 384;
  bf16* w1T    = projwT + 384 * 384;
  bf16* w2T    = w1T + 1536 * 384;
  float* pF    = (float*)(ws + 3539200);
  float* qkv_bF  = pF;
  float* proj_bF = pF + 1152;
  float* mlp_b1F = pF + 1536;
  float* mlp_b2F = pF + 3072;
  float* ln1gF   = pF + 3456;
  float* ln1bF   = pF + 3840;
  float* ln2gF   = pF + 4224;
  float* ln2bF   = pF + 4608;
  bf16* x2 = (bf16*)(ws + 3559168);
  char* basep = ws + 80629504ULL;
  const size_t avail = (ws_size > 80629504ULL) ? (ws_size - 80629504ULL) : 0;

  // chunk sizes: biggest that fits (fewest launches)
  int Wc = 128;  // windows per attention chunk (needs Wc*49*1536*2 B)
  { const int cand[5] = {2048, 1024, 512, 256, 128};
    for (int i = 0; i < 5; ++i)
      if ((size_t)cand[i] * 49 * 1536 * 2 <= avail) { Wc = cand[i]; break; } }
  int Rc = 6272;  // rows per MLP chunk (needs Rc*1920*2 B); divides 100352, mult of 128
  { const int cand[5] = {100352, 50176, 25088, 12544, 6272};
    for (int i = 0; i < 5; ++i)
      if ((size_t)cand[i] * 1920 * 2 <= avail) { Rc = cand[i]; break; } }

  // 1) dtype probe
  probe_k<<<1, 256, 0, stream>>>((const u32*)x, flag);

  // 2) canonical params + transposed bf16 weights
  cvt_params_k<<<20, 256, 0, stream>>>(qkv_b, proj_b, mlp_b1, mlp_b2,
                                       ln1_g, ln1_b, ln2_g, ln2_b, pF, flag);
  transpose_k<<<dim3(36, 12), 256, 0, stream>>>(qkv_w, (u16*)qkvwT, 384, 1152, flag);
  transpose_k<<<dim3(12, 12), 256, 0, stream>>>(proj_w, (u16*)projwT, 384, 384, flag);
  transpose_k<<<dim3(48, 12), 256, 0, stream>>>(mlp_w1, (u16*)w1T, 384, 1536, flag);
  transpose_k<<<dim3(12, 48), 256, 0, stream>>>(mlp_w2, (u16*)w2T, 1536, 384, flag);

  // 3) attention path, chunked over windows: x2 = x + proj(attn(LN1(x)))
  for (int c = 0; c < 2048 / Wc; ++c) {
    const int w0 = c * Wc, t0 = w0 * 49, M = Wc * 49;
    const int nM = M / 128;
    bf16* xn   = (bf16*)basep;            // M x 384 (LN1 windowed -> attn_out)
    bf16* qkvb = xn + (size_t)M * 384;    // M x 1152
    ln_kernel<1><<<M / 4, 256, 0, stream>>>(x, ln1gF, ln1bF, (u32*)xn, flag, 1, t0);
    gemm128<0><<<dim3(9 * nM), 256, 0, stream>>>(xn, qkvwT, qkvb, qkv_bF, nullptr, flag,
                                                 384, 1152, 384, 0, 9);
    attn_kernel<<<Wc * 3, 256, 0, stream>>>(qkvb, xn);
    gemm128<1><<<dim3(3 * nM), 256, 0, stream>>>(xn, projwT, x2, proj_bF, x, flag,
                                                 384, 384, 384, t0, 3);
  }

  // 4) MLP path, chunked over rows: d_out = x2 + mlp(LN2(x2))
  for (int c = 0; c < 100352 / Rc; ++c) {
    const int r0 = c * Rc;
    const int nM = Rc / 128;
    bf16* xn2 = (bf16*)basep;             // Rc x 384
    bf16* hb  = xn2 + (size_t)Rc * 384;   // Rc x 1536
    ln_kernel<0><<<Rc / 4, 256, 0, stream>>>(x2, ln2gF, ln2bF, (u32*)xn2, flag, 0, r0);
    gemm128<2><<<dim3(12 * nM), 256, 0, stream>>>(xn2, w1T, hb, mlp_b1F, nullptr, flag,
                                                  384, 1536, 384, 0, 12);
    gemm128<3><<<dim3(3 * nM), 256, 0, stream>>>(hb, w2T, d_out, mlp_b2F,
                                                 x2 + (size_t)r0 * 384, flag,
                                                 1536, 384, 1536, r0, 3);
  }
}